// Round 1
// baseline (536.756 us; speedup 1.0000x reference)
//
#include <hip/hip_runtime.h>
#include <math.h>

// Problem constants (from reference)
#define T_TOK 4096
#define D_DIM 2048
#define NEXP  64
#define CAP   160            // floor(2*1.25*4096/64)=160, even, >=4

// Merged kernel config
#define NG 128               // GEMM blocks (BM=32 tokens each -> 4096/32)
#define NZ 2048              // zero-fill blocks
#define BM 32
#define BN 64
#define BK 32

// ---------------------------------------------------------------------------
// Kernel 1: blocks [0,NG) compute logits tile + top2 + softmax -> workspace;
//           blocks [NG,NG+NZ) zero-fill the 335.5 MB output concurrently.
// ---------------------------------------------------------------------------
__global__ __launch_bounds__(256) void fused_main(
    const float* __restrict__ x, const float* __restrict__ wg,
    float* __restrict__ out, int out_size,
    int* __restrict__ topi, float* __restrict__ topw)
{
    const int bid = blockIdx.x;
    const int tid = threadIdx.x;

    if (bid >= NG) {
        // ---- zero-fill path ----
        const int zb = bid - NG;
        const size_t n4 = (size_t)out_size >> 2;
        float4* o4 = (float4*)out;
        const float4 z = make_float4(0.f, 0.f, 0.f, 0.f);
        const size_t stride = (size_t)NZ * 256;
        for (size_t i = (size_t)zb * 256 + tid; i < n4; i += stride)
            o4[i] = z;
        if (zb == 0 && tid == 0) {
            for (size_t i = n4 << 2; i < (size_t)out_size; ++i) out[i] = 0.f;
        }
        return;
    }

    // ---- GEMM path: logits[t0..t0+31][0..63] = x @ wg^T ----
    __shared__ float sA[BK][BM + 1];   // [k][token]
    __shared__ float sB[BK][BN + 1];   // [k][expert]
    __shared__ float sL[BM][BN + 1];   // logits tile [token][expert]

    const int t0 = bid * BM;
    const int tx = tid & 15;           // expert group: 4*tx .. 4*tx+3
    const int ty = tid >> 4;           // token group : 2*ty .. 2*ty+1

    float acc[2][4];
#pragma unroll
    for (int r = 0; r < 2; ++r)
#pragma unroll
        for (int j = 0; j < 4; ++j) acc[r][j] = 0.f;

    for (int k0 = 0; k0 < D_DIM; k0 += BK) {
        // stage A tile: 32 tokens x 32 k  (256 x float4)
        {
            const int m  = tid >> 3;
            const int kk = (tid & 7) << 2;
            const float4 v = *(const float4*)(x + (size_t)(t0 + m) * D_DIM + k0 + kk);
            sA[kk + 0][m] = v.x; sA[kk + 1][m] = v.y;
            sA[kk + 2][m] = v.z; sA[kk + 3][m] = v.w;
        }
        // stage B tile: 64 experts x 32 k (512 x float4 -> 2 per thread)
#pragma unroll
        for (int r = 0; r < 2; ++r) {
            const int e  = (tid >> 3) + r * 32;
            const int kk = (tid & 7) << 2;
            const float4 v = *(const float4*)(wg + (size_t)e * D_DIM + k0 + kk);
            sB[kk + 0][e] = v.x; sB[kk + 1][e] = v.y;
            sB[kk + 2][e] = v.z; sB[kk + 3][e] = v.w;
        }
        __syncthreads();
#pragma unroll
        for (int kk = 0; kk < BK; ++kk) {
            const float a0 = sA[kk][2 * ty];
            const float a1 = sA[kk][2 * ty + 1];
            const float b0 = sB[kk][4 * tx + 0];
            const float b1 = sB[kk][4 * tx + 1];
            const float b2 = sB[kk][4 * tx + 2];
            const float b3 = sB[kk][4 * tx + 3];
            acc[0][0] += a0 * b0; acc[0][1] += a0 * b1;
            acc[0][2] += a0 * b2; acc[0][3] += a0 * b3;
            acc[1][0] += a1 * b0; acc[1][1] += a1 * b1;
            acc[1][2] += a1 * b2; acc[1][3] += a1 * b3;
        }
        __syncthreads();
    }

    // dump logits tile to LDS
#pragma unroll
    for (int r = 0; r < 2; ++r)
#pragma unroll
        for (int j = 0; j < 4; ++j)
            sL[2 * ty + r][4 * tx + j] = acc[r][j];
    __syncthreads();

    // top-2 + softmax over the two kept logits (one thread per token).
    // Scan ascending with strict '>' => stable tie-break (lower index first),
    // matching jax.lax.top_k semantics.
    if (tid < BM) {
        const int m = tid;
        float v1 = -INFINITY, v2 = -INFINITY;
        int i1 = 0, i2 = 0;
        for (int e = 0; e < NEXP; ++e) {
            const float v = sL[m][e];
            if (v > v1)      { v2 = v1; i2 = i1; v1 = v; i1 = e; }
            else if (v > v2) { v2 = v;  i2 = e; }
        }
        const float r  = expf(v2 - v1);       // <= 1
        const float s  = 1.0f / (1.0f + r);
        const int   gt = t0 + m;
        topi[2 * gt + 0] = i1;
        topi[2 * gt + 1] = i2;
        topw[2 * gt + 0] = s;
        topw[2 * gt + 1] = r * s;
    }
}

// ---------------------------------------------------------------------------
// Kernel 2: ordered capacity assignment + scatter. One wave (64 lanes).
// Attempts f = t*2 + k processed in flattened order, 64 per chunk.
// Within-chunk per-expert ordering via 6-bit ballot match-any + prefix popcnt.
// ---------------------------------------------------------------------------
__global__ __launch_bounds__(64) void scatter_assign(
    const int* __restrict__ topi, const float* __restrict__ topw,
    float* __restrict__ out)
{
    __shared__ int cnt[NEXP];
    const int lane = threadIdx.x;
    cnt[lane] = 0;
    __syncthreads();

    float* __restrict__ cb   = out + NEXP;
    float* __restrict__ mask = out + NEXP + (size_t)T_TOK * NEXP * CAP;

    const unsigned long long lt = ((unsigned long long)1 << lane) - 1ull;

    for (int c = 0; c < (T_TOK * 2) / 64; ++c) {
        const int f = c * 64 + lane;
        const int e = topi[f];

        // match-any: mask of lanes whose expert == mine
        unsigned long long m = ~0ull;
#pragma unroll
        for (int b = 0; b < 6; ++b) {
            const unsigned long long vb = __ballot((e >> b) & 1);
            m &= ((e >> b) & 1) ? vb : ~vb;
        }
        const int p     = __popcll(m & lt);   // my rank within chunk for expert e
        const int total = __popcll(m);
        const int base  = cnt[e];             // all lanes read before any write
        const int slot  = base + p;
        if (p == 0) cnt[e] = base + total;    // one leader per distinct expert

        if (slot < CAP) {
            const int t = f >> 1;
            const size_t off = ((size_t)t * NEXP + e) * CAP + slot;
            cb[off]   = topw[f];
            mask[off] = 1.0f;
        }
        __syncthreads();                      // carry cnt[] to next chunk
    }

    int used = cnt[lane];
    if (used > CAP) used = CAP;
    out[lane] = (float)used;                  // used_capacity as float
}

// ---------------------------------------------------------------------------
extern "C" void kernel_launch(void* const* d_in, const int* in_sizes, int n_in,
                              void* d_out, int out_size, void* d_ws, size_t ws_size,
                              hipStream_t stream)
{
    const float* x  = (const float*)d_in[0];   // [4096, 2048]
    const float* wg = (const float*)d_in[1];   // [64, 2048]
    float* out = (float*)d_out;

    // workspace: 8192 ints (top indices) + 8192 floats (top weights) = 64 KB
    int*   topi = (int*)d_ws;
    float* topw = (float*)(topi + T_TOK * 2);

    fused_main<<<NG + NZ, 256, 0, stream>>>(x, wg, out, out_size, topi, topw);
    scatter_assign<<<1, 64, 0, stream>>>(topi, topw, out);
}

// Round 2
// 459.896 us; speedup vs baseline: 1.1671x; 1.1671x over previous
//
#include <hip/hip_runtime.h>
#include <math.h>

// Problem constants (from reference)
#define T_TOK 4096
#define D_DIM 2048
#define NEXP  64
#define CAP   160            // floor(2*1.25*4096/64)=160, even, >=4

// Kernel-1 config
#define TPB   4              // tokens per GEMM block (one wave per token at reduce)
#define NGB   (T_TOK / TPB)  // 1024 GEMM blocks
#define NZB   2048           // zero-fill blocks

typedef float vfloat4 __attribute__((ext_vector_type(4)));

// ---------------------------------------------------------------------------
// Kernel 1: blocks [0,NGB) compute logits (register-resident GEMM, no LDS in
// the K-loop) + cross-wave K-reduce + shuffle top-2 + softmax -> workspace;
// blocks [NGB,NGB+NZB) zero-fill the 335.5 MB output concurrently.
//
// GEMM structure: lane = expert (64 lanes = 64 experts). Block owns TPB=4
// tokens; wave w covers k in [w*512, (w+1)*512). wg[e][k] streams through
// VGPRs (contiguous 128B per lane per chunk -> full cache-line use, wg is
// L2-resident at 512KB). x[t][k] addresses are wave-uniform -> scalar loads,
// so the inner loop is v_fmac v_acc, s_x, v_b with zero LDS traffic.
// ---------------------------------------------------------------------------
__global__ __launch_bounds__(256) void fused_main(
    const float* __restrict__ x, const float* __restrict__ wg,
    float* __restrict__ out, int out_size,
    int* __restrict__ topi, float* __restrict__ topw)
{
    const int bid = blockIdx.x;
    const int tid = threadIdx.x;

    if (bid >= NGB) {
        // ---- zero-fill path (memory-roofline: must write out_size*4B) ----
        const int zb = bid - NGB;
        const size_t n4 = (size_t)out_size >> 2;
        vfloat4* o4 = (vfloat4*)out;
        const vfloat4 z = {0.f, 0.f, 0.f, 0.f};
        const size_t stride = (size_t)NZB * 256;
        for (size_t i = (size_t)zb * 256 + tid; i < n4; i += stride)
            __builtin_nontemporal_store(z, &o4[i]);
        if (zb == 0 && tid == 0) {
            for (size_t i = n4 << 2; i < (size_t)out_size; ++i) out[i] = 0.f;
        }
        return;
    }

    // ---- GEMM path ----
    const int e    = tid & 63;                                   // expert = lane
    const int w    = __builtin_amdgcn_readfirstlane(tid >> 6);   // wave id (uniform)
    const int tok0 = bid * TPB;
    const int wk0  = w * (D_DIM / 4);                            // this wave's K range

    float acc[TPB] = {0.f, 0.f, 0.f, 0.f};

    const float* __restrict__ wrow = wg + (size_t)e * D_DIM + wk0;

    for (int c = 0; c < (D_DIM / 4) / 32; ++c) {                 // 16 chunks of 32 k
        vfloat4 b[8];
#pragma unroll
        for (int j = 0; j < 8; ++j)
            b[j] = *(const vfloat4*)(wrow + c * 32 + j * 4);
#pragma unroll
        for (int t = 0; t < TPB; ++t) {
            const float* __restrict__ xp =
                x + (size_t)(tok0 + t) * D_DIM + wk0 + c * 32;   // wave-uniform addr
            float s = 0.f;
#pragma unroll
            for (int j = 0; j < 8; ++j) {
                s += xp[j*4+0] * b[j].x + xp[j*4+1] * b[j].y
                   + xp[j*4+2] * b[j].z + xp[j*4+3] * b[j].w;
            }
            acc[t] += s;
        }
    }

    // cross-wave K-reduce through 4KB LDS
    __shared__ float sAcc[4][TPB][NEXP];
#pragma unroll
    for (int t = 0; t < TPB; ++t)
        sAcc[w][t][e] = acc[t];
    __syncthreads();

    // wave w now owns token w of this block; lane = expert
    const int t = w;
    float v = sAcc[0][t][e] + sAcc[1][t][e] + sAcc[2][t][e] + sAcc[3][t][e];

    // top-2 via 6-step xor-butterfly; tie-break: lower index wins (lax.top_k)
    float v1 = v;         int i1 = e;
    float v2 = -INFINITY; int i2 = NEXP;
#pragma unroll
    for (int off = 32; off >= 1; off >>= 1) {
        const float ov1 = __shfl_xor(v1, off, 64);
        const int   oi1 = __shfl_xor(i1, off, 64);
        const float ov2 = __shfl_xor(v2, off, 64);
        const int   oi2 = __shfl_xor(i2, off, 64);
        const bool firstMine = (v1 > ov1) || (v1 == ov1 && i1 < oi1);
        const float n1  = firstMine ? v1  : ov1;
        const int   ni1 = firstMine ? i1  : oi1;
        const float c1  = firstMine ? ov1 : v1;    // loser of the firsts
        const int   ci1 = firstMine ? oi1 : i1;
        const float c2  = firstMine ? v2  : ov2;   // winner's second
        const int   ci2 = firstMine ? i2  : oi2;
        const bool secondC1 = (c1 > c2) || (c1 == c2 && ci1 < ci2);
        v1 = n1;                      i1 = ni1;
        v2 = secondC1 ? c1 : c2;      i2 = secondC1 ? ci1 : ci2;
    }

    if (e == 0) {
        const int gt = tok0 + t;
        const float r  = expf(v2 - v1);        // <= 1
        const float s1 = 1.0f / (1.0f + r);
        topi[2 * gt + 0] = i1;
        topi[2 * gt + 1] = i2;
        topw[2 * gt + 0] = s1;
        topw[2 * gt + 1] = r * s1;
    }
}

// ---------------------------------------------------------------------------
// Kernel 2: ordered capacity assignment + scatter. One wave (64 lanes), no
// barriers (single-wave LDS ops are program-ordered). Attempts f = t*2+k in
// flattened order, 64 per chunk; within-chunk per-expert rank via 6-bit
// ballot match-any + prefix popcount. Next chunk's inputs are prefetched.
// ---------------------------------------------------------------------------
__global__ __launch_bounds__(64) void scatter_assign(
    const int* __restrict__ topi, const float* __restrict__ topw,
    float* __restrict__ out)
{
    __shared__ int cnt[NEXP];
    const int lane = threadIdx.x;
    cnt[lane] = 0;
    __syncthreads();

    float* __restrict__ cb   = out + NEXP;
    float* __restrict__ mask = out + NEXP + (size_t)T_TOK * NEXP * CAP;

    const unsigned long long lt = ((unsigned long long)1 << lane) - 1ull;
    const int NCH = (T_TOK * 2) / 64;   // 128 chunks

    int   e  = topi[lane];
    float tw = topw[lane];

    for (int c = 0; c < NCH; ++c) {
        // prefetch next chunk (hides global-load latency behind ballot work)
        int   en  = 0;
        float twn = 0.f;
        if (c + 1 < NCH) {
            en  = topi[(c + 1) * 64 + lane];
            twn = topw[(c + 1) * 64 + lane];
        }

        // match-any: mask of lanes whose expert == mine
        unsigned long long m = ~0ull;
#pragma unroll
        for (int b = 0; b < 6; ++b) {
            const unsigned long long vb = __ballot((e >> b) & 1);
            m &= ((e >> b) & 1) ? vb : ~vb;
        }
        const int p     = __popcll(m & lt);   // my rank within chunk for expert e
        const int base  = cnt[e];             // all lanes read before leader write
        const int slot  = base + p;
        if (p == 0) cnt[e] = base + __popcll(m);

        if (slot < CAP) {
            const int f = c * 64 + lane;
            const int t = f >> 1;
            const size_t off = ((size_t)t * NEXP + e) * CAP + slot;
            cb[off]   = tw;
            mask[off] = 1.0f;
        }
        e = en; tw = twn;
    }

    int used = cnt[lane];
    if (used > CAP) used = CAP;
    out[lane] = (float)used;                  // used_capacity as float
}

// ---------------------------------------------------------------------------
extern "C" void kernel_launch(void* const* d_in, const int* in_sizes, int n_in,
                              void* d_out, int out_size, void* d_ws, size_t ws_size,
                              hipStream_t stream)
{
    const float* x  = (const float*)d_in[0];   // [4096, 2048]
    const float* wg = (const float*)d_in[1];   // [64, 2048]
    float* out = (float*)d_out;

    // workspace: 8192 ints (top indices) + 8192 floats (top weights) = 64 KB
    int*   topi = (int*)d_ws;
    float* topw = (float*)(topi + T_TOK * 2);

    fused_main<<<NGB + NZB, 256, 0, stream>>>(x, wg, out, out_size, topi, topw);
    scatter_assign<<<1, 64, 0, stream>>>(topi, topw, out);
}